// Round 13
// baseline (327.366 us; speedup 1.0000x reference)
//
#include <hip/hip_runtime.h>
#include <math.h>

constexpr int   NGc    = 128;
constexpr int   NCELL  = NGc * NGc;
constexpr int   NBIN   = 128 * 128;         // exact-cell bins (bx, by)
constexpr float DTc    = 1e-4f;
constexpr float DXc    = 1.0f / 128.0f;
constexpr float INV_DX = 128.0f;
constexpr float P_VOLc = (DXc * 0.5f) * (DXc * 0.5f);
constexpr float P_MASSc = P_VOLc * 1.0f;
constexpr float GRAV   = 9.8f;
constexpr float STRESS_COEF = -DTc * P_VOLc * 4.0f * INV_DX * INV_DX;

// key = bin<<18 | global within-bin rank
constexpr int KEY_SHIFT = 18;
constexpr unsigned KEY_MASK = (1u << KEY_SHIFT) - 1u;

constexpr int S1_PPT = 4;
constexpr int S1_BLK = 1024;

// ---------------------------------------------------------------------------
// Merged bin+scan (non-cooperative last-block pattern). R9's bin (LDS hist,
// S1_PPT=4, global-atomic flush) + the 16K scan executed by the LAST block
// to finish (done-counter + threadfence; all 245 blocks co-resident, gcnt
// atomics are device-scope). Cuts dispatches 6 -> 5: bottom-up kernel time
// sums to ~140us vs 254 measured, so ~110us is boundary overhead; R11's
// cooperative fusion regressed (graph-capture tax) but this pattern keeps
// plain launches. Scan reuses the dead hist LDS.
// ---------------------------------------------------------------------------
__global__ __launch_bounds__(1024) void binscan_kernel(
    const float2* __restrict__ x, unsigned* __restrict__ key,
    unsigned* __restrict__ gcnt, unsigned* __restrict__ done,
    unsigned* __restrict__ binoff, int n, int nblk)
{
    __shared__ unsigned hist[NBIN];
    __shared__ bool is_last;
#pragma unroll
    for (int j = 0; j < NBIN / S1_BLK; j++)
        hist[threadIdx.x + j * S1_BLK] = 0;
    __syncthreads();

    int base_i = blockIdx.x * (S1_BLK * S1_PPT);
    unsigned t_arr[S1_PPT], r_arr[S1_PPT];
#pragma unroll
    for (int k = 0; k < S1_PPT; k++) {
        int i = base_i + k * S1_BLK + threadIdx.x;
        unsigned t = 0, r = 0;
        if (i < n) {
            float2 xi = x[i];
            int bx = (int)floorf(xi.x * INV_DX - 0.5f);
            int by = (int)floorf(xi.y * INV_DX - 0.5f);
            t = (unsigned)(bx * 128 + by);
            r = atomicAdd(&hist[t], 1u);
        }
        t_arr[k] = t; r_arr[k] = r;
    }
    __syncthreads();

    // flush: hist[b] <- this block's global base within bin b
#pragma unroll
    for (int j = 0; j < NBIN / S1_BLK; j++) {
        int b = threadIdx.x + j * S1_BLK;
        unsigned c = hist[b];
        __syncthreads();
        hist[b] = c ? atomicAdd(&gcnt[b], c) : 0u;
        __syncthreads();
    }

#pragma unroll
    for (int k = 0; k < S1_PPT; k++) {
        int i = base_i + k * S1_BLK + threadIdx.x;
        if (i < n)
            key[i] = (t_arr[k] << KEY_SHIFT) | (hist[t_arr[k]] + r_arr[k]);
    }

    // ---- last-block scan ----
    __threadfence();                 // release this block's work
    __syncthreads();
    if (threadIdx.x == 0) {
        unsigned d = atomicAdd(done, 1u);
        is_last = (d == (unsigned)(nblk - 1));
    }
    __syncthreads();
    if (!is_last) return;
    __threadfence();                 // acquire all blocks' gcnt atomics

    unsigned* s = hist;              // reuse dead hist LDS
    int t = threadIdx.x;
    unsigned v[16];
    unsigned p = 0;
#pragma unroll
    for (int k = 0; k < 16; k++) { v[k] = gcnt[16 * t + k]; p += v[k]; }
    s[t] = p;
    __syncthreads();
    for (int d = 1; d < 1024; d <<= 1) {
        unsigned add = (t >= d) ? s[t - d] : 0u;
        __syncthreads();
        s[t] += add;
        __syncthreads();
    }
    unsigned base = s[t] - p;
#pragma unroll
    for (int k = 0; k < 16; k++) { binoff[16 * t + k] = base; base += v[k]; }
    if (t == 1023) binoff[NBIN] = s[1023];
}

// ---------------------------------------------------------------------------
// Stage A (proven R5 form): readlane-broadcast weights, 1 particle/thread,
// four independent accumulator chains per pass (ILP hides RL->fmac latency).
// VALU-issue-bound at ~69us; VGPR 52, Occ ~34%. Do not restructure.
// ---------------------------------------------------------------------------
#define RL(v, l) __int_as_float(__builtin_amdgcn_readlane(__float_as_int(v), (l)))

__global__ __launch_bounds__(256) void stagea_kernel(
    const float2* __restrict__ x, const float2* __restrict__ v,
    const float4* __restrict__ C, const float4* __restrict__ F,
    const float* __restrict__ W1, const float* __restrict__ b1,
    const float* __restrict__ W2, const float* __restrict__ b2,
    const float* __restrict__ W3, const float* __restrict__ b3,
    const float* __restrict__ W4,
    const unsigned* __restrict__ key, const unsigned* __restrict__ binoff,
    float4* __restrict__ recs, float4* __restrict__ out_F, int n)
{
    const int lane = threadIdx.x & 63;

    // lane-distributed weights (10 VGPRs/lane), loaded by ALL lanes
    float w2r[4], w3r[4];
#pragma unroll
    for (int r = 0; r < 4; r++) {
        w2r[r] = W2[r * 64 + lane];
        w3r[r] = W3[r * 64 + lane];
    }
    // wa: lanes 0..31 = W1[0..31], 32..47 = b1[0..15], 48..63 = W4[0..15]
    float wa = (lane < 32) ? W1[lane]
             : ((lane < 48) ? b1[lane - 32] : W4[lane - 48]);
    // wb: lanes 0..15 = b2[0..15], 16..31 = b3[0..15]
    float wb = (lane < 16) ? b2[lane]
             : ((lane < 32) ? b3[lane - 16] : 0.0f);

    int i = blockIdx.x * 256 + threadIdx.x;
    if (i >= n) return;

    float2 xi = x[i];
    float2 vi = v[i];
    float4 Ci = C[i];
    float4 Fi = F[i];

    float Fn00 = Fi.x + DTc * (Ci.x * Fi.x + Ci.y * Fi.z);
    float Fn01 = Fi.y + DTc * (Ci.x * Fi.y + Ci.y * Fi.w);
    float Fn10 = Fi.z + DTc * (Ci.z * Fi.x + Ci.w * Fi.z);
    float Fn11 = Fi.w + DTc * (Ci.z * Fi.y + Ci.w * Fi.w);

    out_F[i] = make_float4(Fn00, Fn01, Fn10, Fn11);

    float Cm00 = Fn00 * Fn00 + Fn10 * Fn10;
    float Cm01 = Fn00 * Fn01 + Fn10 * Fn11;
    float Cm11 = Fn01 * Fn01 + Fn11 * Fn11;

    float tr  = Cm00 + Cm11;
    float det = Cm00 * Cm11 - Cm01 * Cm01;
    float g   = tr * tr - 4.0f * det;
    float gate = (g > 1e-8f) ? 1.0f : 0.0f;
    float delta = sqrtf(fmaxf(g, 1e-8f));
    float feat0 = 0.5f * (tr + delta);
    float feat1 = 0.5f * (tr - delta);

    // ---- L1 ----
    float h1[16];
#pragma unroll
    for (int j = 0; j < 16; j++) {
        float a = RL(wa, 2 * j) * feat0 + RL(wa, 2 * j + 1) * feat1 + RL(wa, 32 + j);
        h1[j] = fmaxf(a, 0.0f);
    }

    // ---- L2: h2[j] = relu(b2[j] + sum_k W2[16j+k] h1[k]) ----
    float h2[16];
#pragma unroll
    for (int j = 0; j < 16; j++) {
        float a0 = RL(wb, j), a1 = 0.0f, a2 = 0.0f, a3 = 0.0f;
#pragma unroll
        for (int k = 0; k < 16; k += 4) {
            a0 += RL(w2r[(16 * j + k + 0) >> 6], (16 * j + k + 0) & 63) * h1[k + 0];
            a1 += RL(w2r[(16 * j + k + 1) >> 6], (16 * j + k + 1) & 63) * h1[k + 1];
            a2 += RL(w2r[(16 * j + k + 2) >> 6], (16 * j + k + 2) & 63) * h1[k + 2];
            a3 += RL(w2r[(16 * j + k + 3) >> 6], (16 * j + k + 3) & 63) * h1[k + 3];
        }
        h2[j] = fmaxf((a0 + a1) + (a2 + a3), 0.0f);
    }

    // ---- L3 fused with dh3: dh3[j] = (b3[j]+W3[j]·h2 > 0) ? W4[j] : 0 ----
    float dh3[16];
#pragma unroll
    for (int j = 0; j < 16; j++) {
        float a0 = RL(wb, 16 + j), a1 = 0.0f, a2 = 0.0f, a3 = 0.0f;
#pragma unroll
        for (int k = 0; k < 16; k += 4) {
            a0 += RL(w3r[(16 * j + k + 0) >> 6], (16 * j + k + 0) & 63) * h2[k + 0];
            a1 += RL(w3r[(16 * j + k + 1) >> 6], (16 * j + k + 1) & 63) * h2[k + 1];
            a2 += RL(w3r[(16 * j + k + 2) >> 6], (16 * j + k + 2) & 63) * h2[k + 2];
            a3 += RL(w3r[(16 * j + k + 3) >> 6], (16 * j + k + 3) & 63) * h2[k + 3];
        }
        float a = (a0 + a1) + (a2 + a3);
        dh3[j] = (a > 0.0f) ? RL(wa, 48 + j) : 0.0f;
    }

    // ---- Backward W3^T: dh2[k] = relu'(h2[k]) * sum_j W3[16j+k] dh3[j] ----
    float dh2[16];
#pragma unroll
    for (int kk = 0; kk < 16; kk++) {
        float a0 = 0.0f, a1 = 0.0f, a2 = 0.0f, a3 = 0.0f;
#pragma unroll
        for (int j = 0; j < 16; j += 4) {
            a0 += RL(w3r[(16 * (j + 0) + kk) >> 6], (16 * (j + 0) + kk) & 63) * dh3[j + 0];
            a1 += RL(w3r[(16 * (j + 1) + kk) >> 6], (16 * (j + 1) + kk) & 63) * dh3[j + 1];
            a2 += RL(w3r[(16 * (j + 2) + kk) >> 6], (16 * (j + 2) + kk) & 63) * dh3[j + 2];
            a3 += RL(w3r[(16 * (j + 3) + kk) >> 6], (16 * (j + 3) + kk) & 63) * dh3[j + 3];
        }
        float a = (a0 + a1) + (a2 + a3);
        dh2[kk] = (h2[kk] > 0.0f) ? a : 0.0f;
    }

    // ---- Backward W2^T + W1^T ----
    float dfeat0 = 0.0f, dfeat1 = 0.0f;
#pragma unroll
    for (int kk = 0; kk < 16; kk++) {
        float a0 = 0.0f, a1 = 0.0f, a2 = 0.0f, a3 = 0.0f;
#pragma unroll
        for (int j = 0; j < 16; j += 4) {
            a0 += RL(w2r[(16 * (j + 0) + kk) >> 6], (16 * (j + 0) + kk) & 63) * dh2[j + 0];
            a1 += RL(w2r[(16 * (j + 1) + kk) >> 6], (16 * (j + 1) + kk) & 63) * dh2[j + 1];
            a2 += RL(w2r[(16 * (j + 2) + kk) >> 6], (16 * (j + 2) + kk) & 63) * dh2[j + 2];
            a3 += RL(w2r[(16 * (j + 3) + kk) >> 6], (16 * (j + 3) + kk) & 63) * dh2[j + 3];
        }
        float a = (a0 + a1) + (a2 + a3);
        float dh1k = (h1[kk] > 0.0f) ? a : 0.0f;
        dfeat0 += RL(wa, 2 * kk) * dh1k;
        dfeat1 += RL(wa, 2 * kk + 1) * dh1k;
    }

    // ---- epilogue ----
    float half_sum  = 0.5f * (dfeat0 + dfeat1);
    float half_diff = 0.5f * (dfeat0 - dfeat1);
    float inv_delta = 1.0f / delta;
    float dtr  = half_sum + half_diff * tr * inv_delta * gate;
    float ddet = half_diff * (-2.0f) * inv_delta * gate;

    float S00 = 2.0f * (dtr + ddet * Cm11);
    float S11 = 2.0f * (dtr + ddet * Cm00);
    float S01 = -2.0f * ddet * Cm01;

    float dF00 = Fn00 * S00 + Fn01 * S01;
    float dF01 = Fn00 * S01 + Fn01 * S11;
    float dF10 = Fn10 * S00 + Fn11 * S01;
    float dF11 = Fn10 * S01 + Fn11 * S11;

    float a00 = STRESS_COEF * dF00 + P_MASSc * Ci.x;
    float a01 = STRESS_COEF * dF01 + P_MASSc * Ci.y;
    float a10 = STRESS_COEF * dF10 + P_MASSc * Ci.z;
    float a11 = STRESS_COEF * dF11 + P_MASSc * Ci.w;

    unsigned k = key[i];
    unsigned pos = binoff[k >> KEY_SHIFT] + (k & KEY_MASK);

    recs[2 * (size_t)pos]     = make_float4(xi.x, xi.y, a00, a01);
    recs[2 * (size_t)pos + 1] = make_float4(a10, a11, P_MASSc * vi.x, P_MASSc * vi.y);
}

// ---------------------------------------------------------------------------
// Gather-form grid build, exact-cell bins: one wave per node reads exactly
// rows gi-2..gi x cells gj-2..gj; every record is a contributor.
// ---------------------------------------------------------------------------
__global__ __launch_bounds__(256) void grid_gather_kernel(
    const float4* __restrict__ recs, const unsigned* __restrict__ binoff,
    float2* __restrict__ gv)
{
    int wid  = threadIdx.x >> 6;
    int lane = threadIdx.x & 63;
    int node = blockIdx.x * 4 + wid;
    int gi = node >> 7;
    int gj = node & 127;

    const float gxx = (float)gi * DXc;
    const float gxy = (float)gj * DXc;

    float accx = 0.0f, accy = 0.0f, accm = 0.0f;

    int j0 = max(gj - 2, 0);

#pragma unroll
    for (int r = 0; r < 3; r++) {
        int bx = gi - 2 + r;
        if (bx < 0 || bx > 127) continue;
        int lo = (int)binoff[bx * 128 + j0];
        int hi = (int)binoff[bx * 128 + gj + 1];
        for (int k = lo + lane; k < hi; k += 64) {
            float4 r0 = recs[2 * (size_t)k];
            float4 r1 = recs[2 * (size_t)k + 1];

            float py = r0.y * INV_DX;
            int   by = (int)floorf(py - 0.5f);
            int   jj = gj - by;                     // guaranteed 0..2

            float fy = py - (float)by;
            float fx = r0.x * INV_DX - (float)bx;

            float wx;
            if (r == 0)      wx = 0.5f * (fx - 0.5f) * (fx - 0.5f);   // ii = 2
            else if (r == 1) wx = 0.75f - (fx - 1.0f) * (fx - 1.0f);  // ii = 1
            else             wx = 0.5f * (1.5f - fx) * (1.5f - fx);   // ii = 0

            float wy0 = 0.5f * (1.5f - fy) * (1.5f - fy);
            float wy1 = 0.75f - (fy - 1.0f) * (fy - 1.0f);
            float wy2 = 0.5f * (fy - 0.5f) * (fy - 0.5f);
            float wy = (jj == 0) ? wy0 : ((jj == 1) ? wy1 : wy2);

            float wt = wx * wy;
            float dxp = gxx - r0.x;
            float dyp = gxy - r0.y;
            accx += wt * (r1.z + r0.z * dxp + r0.w * dyp);
            accy += wt * (r1.w + r1.x * dxp + r1.y * dyp);
            accm += wt * P_MASSc;
        }
    }

#pragma unroll
    for (int off = 32; off >= 1; off >>= 1) {
        accx += __shfl_xor(accx, off, 64);
        accy += __shfl_xor(accy, off, 64);
        accm += __shfl_xor(accm, off, 64);
    }

    if (lane == 0) {
        float vx = accx, vy = accy;
        if (accm > 0.0f) {
            float inv_m = 1.0f / accm;
            vx *= inv_m;
            vy *= inv_m;
        }
        vy -= DTc * GRAV;
        if (gi < 3)        vx = fmaxf(vx, 0.0f);
        if (gi >= NGc - 3) vx = fminf(vx, 0.0f);
        if (gj < 3)        vy = fmaxf(vy, 0.0f);
        if (gj >= NGc - 3) vy = fminf(vy, 0.0f);
        gv[node] = make_float2(vx, vy);
    }
}

// ---------------------------------------------------------------------------
// G2P (Fnew already written by stagea; no C/F reads here)
// ---------------------------------------------------------------------------
__global__ __launch_bounds__(256) void g2p_kernel(
    const float2* __restrict__ x, const float2* __restrict__ v,
    const int* __restrict__ material, const float* __restrict__ Jp,
    const float2* __restrict__ gv,
    float2* __restrict__ out_x, float2* __restrict__ out_v,
    float4* __restrict__ out_C,
    float* __restrict__ out_mat, float* __restrict__ out_Jp, int n)
{
    int i = blockIdx.x * 256 + threadIdx.x;
    if (i >= n) return;

    float2 xi = x[i];
    float2 vi = v[i];

    float px = xi.x * INV_DX, py = xi.y * INV_DX;
    int   bx = (int)floorf(px - 0.5f);
    int   by = (int)floorf(py - 0.5f);
    float fx = px - (float)bx;
    float fy = py - (float)by;
    float wxs[3] = {0.5f * (1.5f - fx) * (1.5f - fx),
                    0.75f - (fx - 1.0f) * (fx - 1.0f),
                    0.5f * (fx - 0.5f) * (fx - 0.5f)};
    float wys[3] = {0.5f * (1.5f - fy) * (1.5f - fy),
                    0.75f - (fy - 1.0f) * (fy - 1.0f),
                    0.5f * (fy - 0.5f) * (fy - 0.5f)};

    float accvx = 0.0f, accvy = 0.0f;
    float accC00 = 0.0f, accC01 = 0.0f, accC10 = 0.0f, accC11 = 0.0f;

#pragma unroll
    for (int ii = 0; ii < 3; ii++) {
        float gxx = (float)(bx + ii) * DXc;
#pragma unroll
        for (int jj = 0; jj < 3; jj++) {
            float wt = wxs[ii] * wys[jj];
            float2 gvn = gv[(bx + ii) * NGc + (by + jj)];
            float gxy = (float)(by + jj) * DXc;
            accvx  += wt * gvn.x;
            accvy  += wt * gvn.y;
            accC00 += wt * gvn.x * gxx;
            accC01 += wt * gvn.x * gxy;
            accC10 += wt * gvn.y * gxx;
            accC11 += wt * gvn.y * gxy;
        }
    }

    const float k4 = 4.0f * INV_DX * INV_DX;
    out_x[i]   = make_float2(xi.x + DTc * vi.x, xi.y + DTc * vi.y);
    out_v[i]   = make_float2(accvx, accvy);
    out_C[i]   = make_float4(k4 * (accC00 - accvx * xi.x),
                             k4 * (accC01 - accvx * xi.y),
                             k4 * (accC10 - accvy * xi.x),
                             k4 * (accC11 - accvy * xi.y));
    out_mat[i] = (float)material[i];
    out_Jp[i]  = Jp[i];
}

// ---------------------------------------------------------------------------
extern "C" void kernel_launch(void* const* d_in, const int* in_sizes, int n_in,
                              void* d_out, int out_size, void* d_ws, size_t ws_size,
                              hipStream_t stream)
{
    const float2* x  = (const float2*)d_in[0];
    const float2* v  = (const float2*)d_in[1];
    const float4* C  = (const float4*)d_in[2];
    const float4* F  = (const float4*)d_in[3];
    const int* material = (const int*)d_in[4];
    const float* Jp  = (const float*)d_in[5];
    const float* W1  = (const float*)d_in[8];
    const float* b1  = (const float*)d_in[9];
    const float* W2  = (const float*)d_in[10];
    const float* b2  = (const float*)d_in[11];
    const float* W3  = (const float*)d_in[12];
    const float* b3  = (const float*)d_in[13];
    const float* W4  = (const float*)d_in[14];

    const int n = in_sizes[0] / 2;

    // d_ws: gv (NCELL float2, 128KB) — read by g2p so it cannot live in d_out
    float2* gv = (float2*)d_ws;

    float* out = (float*)d_out;
    float2* out_x   = (float2*)out;                    // 0..2N
    float2* out_v   = (float2*)(out + 2 * (size_t)n);  // 2N..4N
    float4* out_C   = (float4*)(out + 4 * (size_t)n);  // 4N..8N
    float4* out_F   = (float4*)(out + 8 * (size_t)n);  // 8N..12N  (written by stagea)
    float*  out_mat = out + 12 * (size_t)n;            // 12N..13N
    float*  out_Jp  = out + 13 * (size_t)n;            // 13N..14N

    // middle-phase scratch inside d_out (consumed before g2p overwrites):
    //  recs at out[0..8N); key at out[12N..13N);
    //  gcnt (NBIN) + done (1) + binoff (NBIN+1) at out[13N..) (out_Jp region,
    //  consumed before g2p writes out_Jp). memset zeroes gcnt+done together.
    float4*   recs   = (float4*)out;
    unsigned* key    = (unsigned*)out_mat;
    unsigned* gcnt   = (unsigned*)(out + 13 * (size_t)n);
    unsigned* done   = gcnt + NBIN;
    unsigned* binoff = done + 1;                       // NBIN+1 entries

    hipMemsetAsync(gcnt, 0, (NBIN + 1) * sizeof(unsigned), stream);

    int s1_blocks = (n + S1_BLK * S1_PPT - 1) / (S1_BLK * S1_PPT);
    int blocks    = (n + 255) / 256;
    binscan_kernel<<<s1_blocks, S1_BLK, 0, stream>>>(x, key, gcnt, done, binoff,
                                                     n, s1_blocks);
    stagea_kernel<<<blocks, 256, 0, stream>>>(x, v, C, F, W1, b1, W2, b2, W3, b3, W4,
                                              key, binoff, recs, out_F, n);
    grid_gather_kernel<<<NCELL / 4, 256, 0, stream>>>(recs, binoff, gv);
    g2p_kernel<<<blocks, 256, 0, stream>>>(x, v, material, Jp, gv,
                                           out_x, out_v, out_C, out_mat, out_Jp, n);
}

// Round 14
// 252.606 us; speedup vs baseline: 1.2960x; 1.2960x over previous
//
#include <hip/hip_runtime.h>
#include <math.h>

constexpr int   NGc    = 128;
constexpr int   NCELL  = NGc * NGc;
constexpr int   NBIN   = 128 * 128;         // exact-cell bins (bx, by)
constexpr float DTc    = 1e-4f;
constexpr float DXc    = 1.0f / 128.0f;
constexpr float INV_DX = 128.0f;
constexpr float P_VOLc = (DXc * 0.5f) * (DXc * 0.5f);
constexpr float P_MASSc = P_VOLc * 1.0f;
constexpr float GRAV   = 9.8f;
constexpr float STRESS_COEF = -DTc * P_VOLc * 4.0f * INV_DX * INV_DX;

// key = bin<<18 | global within-bin rank
constexpr int KEY_SHIFT = 18;
constexpr unsigned KEY_MASK = (1u << KEY_SHIFT) - 1u;

constexpr int S1_PPT = 4;
constexpr int S1_BLK = 1024;

// ---------------------------------------------------------------------------
// S1 (R9 structure, barrier-convoy fixed). R13's reveal: this kernel is
// ~all stall (VALUBusy 0.85%). The old flush loop ran 32 __syncthreads()
// per 16-wave block — both barriers per j are provably unnecessary (thread t
// exclusively owns bins t + j*1024 in the flush: reads hist[b], RMWs
// gcnt[b], writes hist[b]; no cross-thread access). One barrier after the
// full flush suffices (key-write reads arbitrary hist[t_arr]).
// ---------------------------------------------------------------------------
__global__ __launch_bounds__(1024) void bin_kernel(
    const float2* __restrict__ x, unsigned* __restrict__ key,
    unsigned* __restrict__ gcnt, int n)
{
    __shared__ unsigned hist[NBIN];
#pragma unroll
    for (int j = 0; j < NBIN / S1_BLK; j++)
        hist[threadIdx.x + j * S1_BLK] = 0;
    __syncthreads();

    int base_i = blockIdx.x * (S1_BLK * S1_PPT);
    unsigned t_arr[S1_PPT], r_arr[S1_PPT];
#pragma unroll
    for (int k = 0; k < S1_PPT; k++) {
        int i = base_i + k * S1_BLK + threadIdx.x;
        unsigned t = 0, r = 0;
        if (i < n) {
            float2 xi = x[i];
            int bx = (int)floorf(xi.x * INV_DX - 0.5f);
            int by = (int)floorf(xi.y * INV_DX - 0.5f);
            t = (unsigned)(bx * 128 + by);
            r = atomicAdd(&hist[t], 1u);
        }
        t_arr[k] = t; r_arr[k] = r;
    }
    __syncthreads();

    // barrier-free flush: each thread owns its bins exclusively
#pragma unroll
    for (int j = 0; j < NBIN / S1_BLK; j++) {
        int b = threadIdx.x + j * S1_BLK;
        unsigned c = hist[b];
        hist[b] = c ? atomicAdd(&gcnt[b], c) : 0u;
    }
    __syncthreads();

#pragma unroll
    for (int k = 0; k < S1_PPT; k++) {
        int i = base_i + k * S1_BLK + threadIdx.x;
        if (i < n)
            key[i] = (t_arr[k] << KEY_SHIFT) | (hist[t_arr[k]] + r_arr[k]);
    }
}

// ---------------------------------------------------------------------------
// S2: exclusive scan over 16384 bin counts (single block, 16/thread)
// ---------------------------------------------------------------------------
__global__ __launch_bounds__(1024) void scan_kernel(
    const unsigned* __restrict__ gcnt, unsigned* __restrict__ binoff)
{
    __shared__ unsigned s[1024];
    int t = threadIdx.x;
    unsigned v[16];
    unsigned p = 0;
#pragma unroll
    for (int k = 0; k < 16; k++) { v[k] = gcnt[16 * t + k]; p += v[k]; }
    s[t] = p;
    __syncthreads();
    for (int d = 1; d < 1024; d <<= 1) {
        unsigned add = (t >= d) ? s[t - d] : 0u;
        __syncthreads();
        s[t] += add;
        __syncthreads();
    }
    unsigned base = s[t] - p;
#pragma unroll
    for (int k = 0; k < 16; k++) { binoff[16 * t + k] = base; base += v[k]; }
    if (t == 1023) binoff[NBIN] = s[1023];
}

// ---------------------------------------------------------------------------
// Stage A (proven R5 form): readlane-broadcast weights, 1 particle/thread,
// four independent accumulator chains per pass (ILP hides RL->fmac latency).
// VALU-issue-bound at ~69us; VGPR 52, Occ ~34%. Do not restructure.
// ---------------------------------------------------------------------------
#define RL(v, l) __int_as_float(__builtin_amdgcn_readlane(__float_as_int(v), (l)))

__global__ __launch_bounds__(256) void stagea_kernel(
    const float2* __restrict__ x, const float2* __restrict__ v,
    const float4* __restrict__ C, const float4* __restrict__ F,
    const float* __restrict__ W1, const float* __restrict__ b1,
    const float* __restrict__ W2, const float* __restrict__ b2,
    const float* __restrict__ W3, const float* __restrict__ b3,
    const float* __restrict__ W4,
    const unsigned* __restrict__ key, const unsigned* __restrict__ binoff,
    float4* __restrict__ recs, float4* __restrict__ out_F, int n)
{
    const int lane = threadIdx.x & 63;

    // lane-distributed weights (10 VGPRs/lane), loaded by ALL lanes
    float w2r[4], w3r[4];
#pragma unroll
    for (int r = 0; r < 4; r++) {
        w2r[r] = W2[r * 64 + lane];
        w3r[r] = W3[r * 64 + lane];
    }
    // wa: lanes 0..31 = W1[0..31], 32..47 = b1[0..15], 48..63 = W4[0..15]
    float wa = (lane < 32) ? W1[lane]
             : ((lane < 48) ? b1[lane - 32] : W4[lane - 48]);
    // wb: lanes 0..15 = b2[0..15], 16..31 = b3[0..15]
    float wb = (lane < 16) ? b2[lane]
             : ((lane < 32) ? b3[lane - 16] : 0.0f);

    int i = blockIdx.x * 256 + threadIdx.x;
    if (i >= n) return;

    float2 xi = x[i];
    float2 vi = v[i];
    float4 Ci = C[i];
    float4 Fi = F[i];

    float Fn00 = Fi.x + DTc * (Ci.x * Fi.x + Ci.y * Fi.z);
    float Fn01 = Fi.y + DTc * (Ci.x * Fi.y + Ci.y * Fi.w);
    float Fn10 = Fi.z + DTc * (Ci.z * Fi.x + Ci.w * Fi.z);
    float Fn11 = Fi.w + DTc * (Ci.z * Fi.y + Ci.w * Fi.w);

    out_F[i] = make_float4(Fn00, Fn01, Fn10, Fn11);

    float Cm00 = Fn00 * Fn00 + Fn10 * Fn10;
    float Cm01 = Fn00 * Fn01 + Fn10 * Fn11;
    float Cm11 = Fn01 * Fn01 + Fn11 * Fn11;

    float tr  = Cm00 + Cm11;
    float det = Cm00 * Cm11 - Cm01 * Cm01;
    float g   = tr * tr - 4.0f * det;
    float gate = (g > 1e-8f) ? 1.0f : 0.0f;
    float delta = sqrtf(fmaxf(g, 1e-8f));
    float feat0 = 0.5f * (tr + delta);
    float feat1 = 0.5f * (tr - delta);

    // ---- L1 ----
    float h1[16];
#pragma unroll
    for (int j = 0; j < 16; j++) {
        float a = RL(wa, 2 * j) * feat0 + RL(wa, 2 * j + 1) * feat1 + RL(wa, 32 + j);
        h1[j] = fmaxf(a, 0.0f);
    }

    // ---- L2: h2[j] = relu(b2[j] + sum_k W2[16j+k] h1[k]) ----
    float h2[16];
#pragma unroll
    for (int j = 0; j < 16; j++) {
        float a0 = RL(wb, j), a1 = 0.0f, a2 = 0.0f, a3 = 0.0f;
#pragma unroll
        for (int k = 0; k < 16; k += 4) {
            a0 += RL(w2r[(16 * j + k + 0) >> 6], (16 * j + k + 0) & 63) * h1[k + 0];
            a1 += RL(w2r[(16 * j + k + 1) >> 6], (16 * j + k + 1) & 63) * h1[k + 1];
            a2 += RL(w2r[(16 * j + k + 2) >> 6], (16 * j + k + 2) & 63) * h1[k + 2];
            a3 += RL(w2r[(16 * j + k + 3) >> 6], (16 * j + k + 3) & 63) * h1[k + 3];
        }
        h2[j] = fmaxf((a0 + a1) + (a2 + a3), 0.0f);
    }

    // ---- L3 fused with dh3: dh3[j] = (b3[j]+W3[j]·h2 > 0) ? W4[j] : 0 ----
    float dh3[16];
#pragma unroll
    for (int j = 0; j < 16; j++) {
        float a0 = RL(wb, 16 + j), a1 = 0.0f, a2 = 0.0f, a3 = 0.0f;
#pragma unroll
        for (int k = 0; k < 16; k += 4) {
            a0 += RL(w3r[(16 * j + k + 0) >> 6], (16 * j + k + 0) & 63) * h2[k + 0];
            a1 += RL(w3r[(16 * j + k + 1) >> 6], (16 * j + k + 1) & 63) * h2[k + 1];
            a2 += RL(w3r[(16 * j + k + 2) >> 6], (16 * j + k + 2) & 63) * h2[k + 2];
            a3 += RL(w3r[(16 * j + k + 3) >> 6], (16 * j + k + 3) & 63) * h2[k + 3];
        }
        float a = (a0 + a1) + (a2 + a3);
        dh3[j] = (a > 0.0f) ? RL(wa, 48 + j) : 0.0f;
    }

    // ---- Backward W3^T: dh2[k] = relu'(h2[k]) * sum_j W3[16j+k] dh3[j] ----
    float dh2[16];
#pragma unroll
    for (int kk = 0; kk < 16; kk++) {
        float a0 = 0.0f, a1 = 0.0f, a2 = 0.0f, a3 = 0.0f;
#pragma unroll
        for (int j = 0; j < 16; j += 4) {
            a0 += RL(w3r[(16 * (j + 0) + kk) >> 6], (16 * (j + 0) + kk) & 63) * dh3[j + 0];
            a1 += RL(w3r[(16 * (j + 1) + kk) >> 6], (16 * (j + 1) + kk) & 63) * dh3[j + 1];
            a2 += RL(w3r[(16 * (j + 2) + kk) >> 6], (16 * (j + 2) + kk) & 63) * dh3[j + 2];
            a3 += RL(w3r[(16 * (j + 3) + kk) >> 6], (16 * (j + 3) + kk) & 63) * dh3[j + 3];
        }
        float a = (a0 + a1) + (a2 + a3);
        dh2[kk] = (h2[kk] > 0.0f) ? a : 0.0f;
    }

    // ---- Backward W2^T + W1^T ----
    float dfeat0 = 0.0f, dfeat1 = 0.0f;
#pragma unroll
    for (int kk = 0; kk < 16; kk++) {
        float a0 = 0.0f, a1 = 0.0f, a2 = 0.0f, a3 = 0.0f;
#pragma unroll
        for (int j = 0; j < 16; j += 4) {
            a0 += RL(w2r[(16 * (j + 0) + kk) >> 6], (16 * (j + 0) + kk) & 63) * dh2[j + 0];
            a1 += RL(w2r[(16 * (j + 1) + kk) >> 6], (16 * (j + 1) + kk) & 63) * dh2[j + 1];
            a2 += RL(w2r[(16 * (j + 2) + kk) >> 6], (16 * (j + 2) + kk) & 63) * dh2[j + 2];
            a3 += RL(w2r[(16 * (j + 3) + kk) >> 6], (16 * (j + 3) + kk) & 63) * dh2[j + 3];
        }
        float a = (a0 + a1) + (a2 + a3);
        float dh1k = (h1[kk] > 0.0f) ? a : 0.0f;
        dfeat0 += RL(wa, 2 * kk) * dh1k;
        dfeat1 += RL(wa, 2 * kk + 1) * dh1k;
    }

    // ---- epilogue ----
    float half_sum  = 0.5f * (dfeat0 + dfeat1);
    float half_diff = 0.5f * (dfeat0 - dfeat1);
    float inv_delta = 1.0f / delta;
    float dtr  = half_sum + half_diff * tr * inv_delta * gate;
    float ddet = half_diff * (-2.0f) * inv_delta * gate;

    float S00 = 2.0f * (dtr + ddet * Cm11);
    float S11 = 2.0f * (dtr + ddet * Cm00);
    float S01 = -2.0f * ddet * Cm01;

    float dF00 = Fn00 * S00 + Fn01 * S01;
    float dF01 = Fn00 * S01 + Fn01 * S11;
    float dF10 = Fn10 * S00 + Fn11 * S01;
    float dF11 = Fn10 * S01 + Fn11 * S11;

    float a00 = STRESS_COEF * dF00 + P_MASSc * Ci.x;
    float a01 = STRESS_COEF * dF01 + P_MASSc * Ci.y;
    float a10 = STRESS_COEF * dF10 + P_MASSc * Ci.z;
    float a11 = STRESS_COEF * dF11 + P_MASSc * Ci.w;

    unsigned k = key[i];
    unsigned pos = binoff[k >> KEY_SHIFT] + (k & KEY_MASK);

    recs[2 * (size_t)pos]     = make_float4(xi.x, xi.y, a00, a01);
    recs[2 * (size_t)pos + 1] = make_float4(a10, a11, P_MASSc * vi.x, P_MASSc * vi.y);
}

// ---------------------------------------------------------------------------
// Gather-form grid build, exact-cell bins: one wave per node reads exactly
// rows gi-2..gi x cells gj-2..gj; every record is a contributor.
// ---------------------------------------------------------------------------
__global__ __launch_bounds__(256) void grid_gather_kernel(
    const float4* __restrict__ recs, const unsigned* __restrict__ binoff,
    float2* __restrict__ gv)
{
    int wid  = threadIdx.x >> 6;
    int lane = threadIdx.x & 63;
    int node = blockIdx.x * 4 + wid;
    int gi = node >> 7;
    int gj = node & 127;

    const float gxx = (float)gi * DXc;
    const float gxy = (float)gj * DXc;

    float accx = 0.0f, accy = 0.0f, accm = 0.0f;

    int j0 = max(gj - 2, 0);

#pragma unroll
    for (int r = 0; r < 3; r++) {
        int bx = gi - 2 + r;
        if (bx < 0 || bx > 127) continue;
        int lo = (int)binoff[bx * 128 + j0];
        int hi = (int)binoff[bx * 128 + gj + 1];
        for (int k = lo + lane; k < hi; k += 64) {
            float4 r0 = recs[2 * (size_t)k];
            float4 r1 = recs[2 * (size_t)k + 1];

            float py = r0.y * INV_DX;
            int   by = (int)floorf(py - 0.5f);
            int   jj = gj - by;                     // guaranteed 0..2

            float fy = py - (float)by;
            float fx = r0.x * INV_DX - (float)bx;

            float wx;
            if (r == 0)      wx = 0.5f * (fx - 0.5f) * (fx - 0.5f);   // ii = 2
            else if (r == 1) wx = 0.75f - (fx - 1.0f) * (fx - 1.0f);  // ii = 1
            else             wx = 0.5f * (1.5f - fx) * (1.5f - fx);   // ii = 0

            float wy0 = 0.5f * (1.5f - fy) * (1.5f - fy);
            float wy1 = 0.75f - (fy - 1.0f) * (fy - 1.0f);
            float wy2 = 0.5f * (fy - 0.5f) * (fy - 0.5f);
            float wy = (jj == 0) ? wy0 : ((jj == 1) ? wy1 : wy2);

            float wt = wx * wy;
            float dxp = gxx - r0.x;
            float dyp = gxy - r0.y;
            accx += wt * (r1.z + r0.z * dxp + r0.w * dyp);
            accy += wt * (r1.w + r1.x * dxp + r1.y * dyp);
            accm += wt * P_MASSc;
        }
    }

#pragma unroll
    for (int off = 32; off >= 1; off >>= 1) {
        accx += __shfl_xor(accx, off, 64);
        accy += __shfl_xor(accy, off, 64);
        accm += __shfl_xor(accm, off, 64);
    }

    if (lane == 0) {
        float vx = accx, vy = accy;
        if (accm > 0.0f) {
            float inv_m = 1.0f / accm;
            vx *= inv_m;
            vy *= inv_m;
        }
        vy -= DTc * GRAV;
        if (gi < 3)        vx = fmaxf(vx, 0.0f);
        if (gi >= NGc - 3) vx = fminf(vx, 0.0f);
        if (gj < 3)        vy = fmaxf(vy, 0.0f);
        if (gj >= NGc - 3) vy = fminf(vy, 0.0f);
        gv[node] = make_float2(vx, vy);
    }
}

// ---------------------------------------------------------------------------
// G2P (Fnew already written by stagea; no C/F reads here)
// ---------------------------------------------------------------------------
__global__ __launch_bounds__(256) void g2p_kernel(
    const float2* __restrict__ x, const float2* __restrict__ v,
    const int* __restrict__ material, const float* __restrict__ Jp,
    const float2* __restrict__ gv,
    float2* __restrict__ out_x, float2* __restrict__ out_v,
    float4* __restrict__ out_C,
    float* __restrict__ out_mat, float* __restrict__ out_Jp, int n)
{
    int i = blockIdx.x * 256 + threadIdx.x;
    if (i >= n) return;

    float2 xi = x[i];
    float2 vi = v[i];

    float px = xi.x * INV_DX, py = xi.y * INV_DX;
    int   bx = (int)floorf(px - 0.5f);
    int   by = (int)floorf(py - 0.5f);
    float fx = px - (float)bx;
    float fy = py - (float)by;
    float wxs[3] = {0.5f * (1.5f - fx) * (1.5f - fx),
                    0.75f - (fx - 1.0f) * (fx - 1.0f),
                    0.5f * (fx - 0.5f) * (fx - 0.5f)};
    float wys[3] = {0.5f * (1.5f - fy) * (1.5f - fy),
                    0.75f - (fy - 1.0f) * (fy - 1.0f),
                    0.5f * (fy - 0.5f) * (fy - 0.5f)};

    float accvx = 0.0f, accvy = 0.0f;
    float accC00 = 0.0f, accC01 = 0.0f, accC10 = 0.0f, accC11 = 0.0f;

#pragma unroll
    for (int ii = 0; ii < 3; ii++) {
        float gxx = (float)(bx + ii) * DXc;
#pragma unroll
        for (int jj = 0; jj < 3; jj++) {
            float wt = wxs[ii] * wys[jj];
            float2 gvn = gv[(bx + ii) * NGc + (by + jj)];
            float gxy = (float)(by + jj) * DXc;
            accvx  += wt * gvn.x;
            accvy  += wt * gvn.y;
            accC00 += wt * gvn.x * gxx;
            accC01 += wt * gvn.x * gxy;
            accC10 += wt * gvn.y * gxx;
            accC11 += wt * gvn.y * gxy;
        }
    }

    const float k4 = 4.0f * INV_DX * INV_DX;
    out_x[i]   = make_float2(xi.x + DTc * vi.x, xi.y + DTc * vi.y);
    out_v[i]   = make_float2(accvx, accvy);
    out_C[i]   = make_float4(k4 * (accC00 - accvx * xi.x),
                             k4 * (accC01 - accvx * xi.y),
                             k4 * (accC10 - accvy * xi.x),
                             k4 * (accC11 - accvy * xi.y));
    out_mat[i] = (float)material[i];
    out_Jp[i]  = Jp[i];
}

// ---------------------------------------------------------------------------
extern "C" void kernel_launch(void* const* d_in, const int* in_sizes, int n_in,
                              void* d_out, int out_size, void* d_ws, size_t ws_size,
                              hipStream_t stream)
{
    const float2* x  = (const float2*)d_in[0];
    const float2* v  = (const float2*)d_in[1];
    const float4* C  = (const float4*)d_in[2];
    const float4* F  = (const float4*)d_in[3];
    const int* material = (const int*)d_in[4];
    const float* Jp  = (const float*)d_in[5];
    const float* W1  = (const float*)d_in[8];
    const float* b1  = (const float*)d_in[9];
    const float* W2  = (const float*)d_in[10];
    const float* b2  = (const float*)d_in[11];
    const float* W3  = (const float*)d_in[12];
    const float* b3  = (const float*)d_in[13];
    const float* W4  = (const float*)d_in[14];

    const int n = in_sizes[0] / 2;

    // d_ws: gv (NCELL float2, 128KB) — read by g2p so it cannot live in d_out
    float2* gv = (float2*)d_ws;

    float* out = (float*)d_out;
    float2* out_x   = (float2*)out;                    // 0..2N
    float2* out_v   = (float2*)(out + 2 * (size_t)n);  // 2N..4N
    float4* out_C   = (float4*)(out + 4 * (size_t)n);  // 4N..8N
    float4* out_F   = (float4*)(out + 8 * (size_t)n);  // 8N..12N  (written by stagea)
    float*  out_mat = out + 12 * (size_t)n;            // 12N..13N
    float*  out_Jp  = out + 13 * (size_t)n;            // 13N..14N

    // middle-phase scratch inside d_out (consumed before g2p overwrites):
    //  recs at out[0..8N); key at out[12N..13N);
    //  gcnt (NBIN) + binoff (NBIN+1) at out[13N..) (out_Jp region,
    //  consumed before g2p writes out_Jp)
    float4*   recs   = (float4*)out;
    unsigned* key    = (unsigned*)out_mat;
    unsigned* gcnt   = (unsigned*)(out + 13 * (size_t)n);
    unsigned* binoff = gcnt + NBIN;

    hipMemsetAsync(gcnt, 0, NBIN * sizeof(unsigned), stream);

    int s1_blocks = (n + S1_BLK * S1_PPT - 1) / (S1_BLK * S1_PPT);
    int blocks    = (n + 255) / 256;
    bin_kernel<<<s1_blocks, S1_BLK, 0, stream>>>(x, key, gcnt, n);
    scan_kernel<<<1, 1024, 0, stream>>>(gcnt, binoff);
    stagea_kernel<<<blocks, 256, 0, stream>>>(x, v, C, F, W1, b1, W2, b2, W3, b3, W4,
                                              key, binoff, recs, out_F, n);
    grid_gather_kernel<<<NCELL / 4, 256, 0, stream>>>(recs, binoff, gv);
    g2p_kernel<<<blocks, 256, 0, stream>>>(x, v, material, Jp, gv,
                                           out_x, out_v, out_C, out_mat, out_Jp, n);
}